// Round 7
// baseline (42.867 us; speedup 1.0000x reference)
//
#include <hip/hip_runtime.h>

// MeanPoolingWithoutPadding: features [B,S,D] f32, lengths [B] i32,
// out [B,D] f32 = sum_{s<len[b]} f[b,s,:] / len[b].  B=64, S=2048, D=512.
//
// Single-kernel atomic design (R7). R2-R6's two-phase structure was flat at
// ~30 us vs a ~22 us read floor; the residual was the split-combine
// machinery (16 MB ws round-trip + second dispatch + graph gap). Here each
// block (b,split) sums its per-b-balanced chunk, scales by 1/len[b], and
// atomicAdds (agent-scope RELAXED -> global_atomic_add_f32, NO fences --
// R3's 13x regression was release/acquire fences, not atomics) into out.
// out is zeroed by an on-stream 128 KB memset each call (graph-capturable).
// Rounding: sum of <=32 scaled partials, atomic order varies ~1e-6 --
// validation threshold is 2.28e-2, we sit at ~2e-4.

#define DDIM 512
#define TPB  128
#define NSPLIT 32

__device__ __forceinline__ void acc4(float4& a, const float4& v) {
    a.x += v.x; a.y += v.y; a.z += v.z; a.w += v.w;
}

__global__ void __launch_bounds__(TPB)
pool_atomic(const float* __restrict__ feat, const int* __restrict__ lengths,
            float* __restrict__ out, int S) {
    const int b     = blockIdx.x;
    const int split = blockIdx.y;
    const int tid   = threadIdx.x;
    const int len   = lengths[b];

    const int chunk = (len + NSPLIT - 1) / NSPLIT;  // per-b balanced
    const int s0 = split * chunk;
    if (s0 >= len) return;                          // inactive split
    const int s1 = min(s0 + chunk, len);

    float4 a0 = {0.f, 0.f, 0.f, 0.f};
    float4 a1 = {0.f, 0.f, 0.f, 0.f};
    float4 a2 = {0.f, 0.f, 0.f, 0.f};
    float4 a3 = {0.f, 0.f, 0.f, 0.f};

    const float4* __restrict__ base =
        reinterpret_cast<const float4*>(feat + (size_t)b * S * DDIM) + tid;
    const int ld4 = DDIM / 4;

    int s = s0;
    for (; s + 7 < s1; s += 8) {
        float4 v0 = base[(size_t)(s + 0) * ld4];
        float4 v1 = base[(size_t)(s + 1) * ld4];
        float4 v2 = base[(size_t)(s + 2) * ld4];
        float4 v3 = base[(size_t)(s + 3) * ld4];
        float4 v4 = base[(size_t)(s + 4) * ld4];
        float4 v5 = base[(size_t)(s + 5) * ld4];
        float4 v6 = base[(size_t)(s + 6) * ld4];
        float4 v7 = base[(size_t)(s + 7) * ld4];
        acc4(a0, v0); acc4(a1, v1); acc4(a2, v2); acc4(a3, v3);
        acc4(a0, v4); acc4(a1, v5); acc4(a2, v6); acc4(a3, v7);
    }
    for (; s < s1; ++s) {
        float4 v = base[(size_t)s * ld4];
        acc4(a0, v);
    }
    acc4(a0, a1); acc4(a2, a3); acc4(a0, a2);

    const float inv = 1.0f / (float)len;
    float* op = out + (size_t)b * DDIM + tid * 4;
    __hip_atomic_fetch_add(op + 0, a0.x * inv, __ATOMIC_RELAXED, __HIP_MEMORY_SCOPE_AGENT);
    __hip_atomic_fetch_add(op + 1, a0.y * inv, __ATOMIC_RELAXED, __HIP_MEMORY_SCOPE_AGENT);
    __hip_atomic_fetch_add(op + 2, a0.z * inv, __ATOMIC_RELAXED, __HIP_MEMORY_SCOPE_AGENT);
    __hip_atomic_fetch_add(op + 3, a0.w * inv, __ATOMIC_RELAXED, __HIP_MEMORY_SCOPE_AGENT);
}

// Generic fallback: one block per b, full S loop, no atomics/ws.
__global__ void __launch_bounds__(TPB)
pool_direct(const float* __restrict__ feat, const int* __restrict__ lengths,
            float* __restrict__ out, int S) {
    const int b   = blockIdx.x;
    const int tid = threadIdx.x;
    const int len = lengths[b];
    float4 a0 = {0.f, 0.f, 0.f, 0.f};
    float4 a1 = {0.f, 0.f, 0.f, 0.f};
    float4 a2 = {0.f, 0.f, 0.f, 0.f};
    float4 a3 = {0.f, 0.f, 0.f, 0.f};
    const float4* __restrict__ base =
        reinterpret_cast<const float4*>(feat + (size_t)b * S * DDIM) + tid;
    const int ld4 = DDIM / 4;
    int s = 0;
    for (; s + 3 < len; s += 4) {
        float4 v0 = base[(size_t)(s + 0) * ld4];
        float4 v1 = base[(size_t)(s + 1) * ld4];
        float4 v2 = base[(size_t)(s + 2) * ld4];
        float4 v3 = base[(size_t)(s + 3) * ld4];
        acc4(a0, v0); acc4(a1, v1); acc4(a2, v2); acc4(a3, v3);
    }
    for (; s < len; ++s) { float4 v = base[(size_t)s * ld4]; acc4(a0, v); }
    acc4(a0, a1); acc4(a2, a3); acc4(a0, a2);
    const float inv = 1.0f / (float)len;
    float4 r = {a0.x * inv, a0.y * inv, a0.z * inv, a0.w * inv};
    reinterpret_cast<float4*>(out + (size_t)b * DDIM)[tid] = r;
}

extern "C" void kernel_launch(void* const* d_in, const int* in_sizes, int n_in,
                              void* d_out, int out_size, void* d_ws, size_t ws_size,
                              hipStream_t stream) {
    const float* feat    = (const float*)d_in[0];
    const int*   lengths = (const int*)d_in[1];
    float*       out     = (float*)d_out;

    const int B = in_sizes[1];                       // 64
    const int S = in_sizes[0] / (B * DDIM);          // 2048

    if (out_size == B * DDIM && in_sizes[0] == B * S * DDIM) {
        hipMemsetAsync(out, 0, (size_t)out_size * sizeof(float), stream);
        dim3 grid(B, NSPLIT);
        pool_atomic<<<grid, TPB, 0, stream>>>(feat, lengths, out, S);
    } else {
        pool_direct<<<B, TPB, 0, stream>>>(feat, lengths, out, S);
    }
}

// Round 8
// 29.401 us; speedup vs baseline: 1.4580x; 1.4580x over previous
//
#include <hip/hip_runtime.h>

// MeanPoolingWithoutPadding: features [B,S,D] f32, lengths [B] i32,
// out [B,D] f32 = sum_{s<len[b]} f[b,s,:] / len[b].  B=64, S=2048, D=512.
//
// R8: two-phase, but split BOTH S and D in the partial kernel.
//   pool_partial: grid (B, DQ=4, NS=8) = 2048 blocks x 128 thr. Block
//     (b,q,split) sums rows [split*chunk, ...) of f4-columns [q*32, q*32+32)
//     (512 B/row), chunk = ceil(len/8). 32 col-lanes x 4 row-groups; LDS
//     combine of the 4 row-groups; write one 512 B partial slice.
//     ws = B*NS*D floats = 1 MB total (vs R2's 8 MB) -> 2 MB round-trip
//     instead of 16 MB.
//   pool_final: grid (B,4) x 128 thr; each thread reads <=2 partials (16 B
//     each), LDS combine, scale by 1/len, store. ~1 us.
//   No atomics (R7: cross-XCD f32 atomic RMW serialization, 42.9 us), no
//   device fences (R3: 13x regression).

#define DDIM 512
#define LD4  (DDIM / 4)   // 128 float4 per row
#define NS   8
#define DQ   4
#define TPB  128

__device__ __forceinline__ void acc4(float4& a, const float4& v) {
    a.x += v.x; a.y += v.y; a.z += v.z; a.w += v.w;
}

__global__ void __launch_bounds__(TPB)
pool_partial(const float* __restrict__ feat, const int* __restrict__ lengths,
             float* __restrict__ ws, int S) {
    const int b     = blockIdx.x;
    const int q     = blockIdx.y;        // D-slice
    const int split = blockIdx.z;        // S-slice
    const int t     = threadIdx.x;
    const int lane  = t & 31;            // col lane: 32 f4 = 512 B
    const int rg    = t >> 5;            // row group 0..3

    const int len   = lengths[b];
    const int chunk = (len + NS - 1) / NS;
    const int s0 = split * chunk;
    if (s0 >= len) return;               // inactive: final never reads it
    const int s1 = min(s0 + chunk, len);

    const int col = q * 32 + lane;       // f4 column index
    const float4* __restrict__ base =
        reinterpret_cast<const float4*>(feat + (size_t)b * S * DDIM) + col;

    float4 a0 = {0.f, 0.f, 0.f, 0.f};
    float4 a1 = {0.f, 0.f, 0.f, 0.f};
    float4 a2 = {0.f, 0.f, 0.f, 0.f};
    float4 a3 = {0.f, 0.f, 0.f, 0.f};

    int s = s0 + rg;
    for (; s + 12 < s1; s += 16) {
        float4 v0 = base[(size_t)(s +  0) * LD4];
        float4 v1 = base[(size_t)(s +  4) * LD4];
        float4 v2 = base[(size_t)(s +  8) * LD4];
        float4 v3 = base[(size_t)(s + 12) * LD4];
        acc4(a0, v0); acc4(a1, v1); acc4(a2, v2); acc4(a3, v3);
    }
    for (; s < s1; s += 4) {
        float4 v = base[(size_t)s * LD4];
        acc4(a0, v);
    }
    acc4(a0, a1); acc4(a2, a3); acc4(a0, a2);

    __shared__ float4 red[TPB];
    red[t] = a0;
    __syncthreads();
    if (rg == 0) {
        acc4(a0, red[t + 32]);
        acc4(a0, red[t + 64]);
        acc4(a0, red[t + 96]);
        float4* wsp = reinterpret_cast<float4*>(ws) + ((size_t)b * NS + split) * LD4 + col;
        *wsp = a0;
    }
}

// grid (B, DQ), 128 thr. Thread owns f4-col q*32+lane for split set {rg, rg+4}.
__global__ void __launch_bounds__(TPB)
pool_final(const float* __restrict__ ws, const int* __restrict__ lengths,
           float* __restrict__ out) {
    const int b    = blockIdx.x;
    const int q    = blockIdx.y;
    const int t    = threadIdx.x;
    const int lane = t & 31;
    const int rg   = t >> 5;
    const int col  = q * 32 + lane;

    const int len   = lengths[b];
    const int chunk = (len + NS - 1) / NS;
    const int nact  = (len + chunk - 1) / chunk;   // splits actually written

    const float4* __restrict__ wsp =
        reinterpret_cast<const float4*>(ws) + (size_t)b * NS * LD4 + col;

    float4 a = {0.f, 0.f, 0.f, 0.f};
    for (int p = rg; p < nact; p += 4) {
        acc4(a, wsp[(size_t)p * LD4]);
    }

    __shared__ float4 red[TPB];
    red[t] = a;
    __syncthreads();
    if (rg == 0) {
        acc4(a, red[t + 32]);
        acc4(a, red[t + 64]);
        acc4(a, red[t + 96]);
        const float inv = 1.0f / (float)len;
        float4 r = {a.x * inv, a.y * inv, a.z * inv, a.w * inv};
        reinterpret_cast<float4*>(out + (size_t)b * DDIM)[col] = r;
    }
}

// Generic fallback: one block per b, full S loop, no ws.
__global__ void __launch_bounds__(TPB)
pool_direct(const float* __restrict__ feat, const int* __restrict__ lengths,
            float* __restrict__ out, int S) {
    const int b   = blockIdx.x;
    const int tid = threadIdx.x;
    const int len = lengths[b];
    float4 a0 = {0.f, 0.f, 0.f, 0.f};
    float4 a1 = {0.f, 0.f, 0.f, 0.f};
    float4 a2 = {0.f, 0.f, 0.f, 0.f};
    float4 a3 = {0.f, 0.f, 0.f, 0.f};
    const float4* __restrict__ base =
        reinterpret_cast<const float4*>(feat + (size_t)b * S * DDIM) + tid;
    int s = 0;
    for (; s + 3 < len; s += 4) {
        float4 v0 = base[(size_t)(s + 0) * LD4];
        float4 v1 = base[(size_t)(s + 1) * LD4];
        float4 v2 = base[(size_t)(s + 2) * LD4];
        float4 v3 = base[(size_t)(s + 3) * LD4];
        acc4(a0, v0); acc4(a1, v1); acc4(a2, v2); acc4(a3, v3);
    }
    for (; s < len; ++s) { float4 v = base[(size_t)s * LD4]; acc4(a0, v); }
    acc4(a0, a1); acc4(a2, a3); acc4(a0, a2);
    const float inv = 1.0f / (float)len;
    float4 r = {a0.x * inv, a0.y * inv, a0.z * inv, a0.w * inv};
    reinterpret_cast<float4*>(out + (size_t)b * DDIM)[tid] = r;
}

extern "C" void kernel_launch(void* const* d_in, const int* in_sizes, int n_in,
                              void* d_out, int out_size, void* d_ws, size_t ws_size,
                              hipStream_t stream) {
    const float* feat    = (const float*)d_in[0];
    const int*   lengths = (const int*)d_in[1];
    float*       out     = (float*)d_out;

    const int B = in_sizes[1];                       // 64
    const int S = in_sizes[0] / (B * DDIM);          // 2048

    const size_t need = (size_t)B * NS * DDIM * sizeof(float);

    if (ws_size >= need && out_size == B * DDIM) {
        float* ws = (float*)d_ws;
        dim3 grid1(B, DQ, NS);
        dim3 grid2(B, DQ);
        pool_partial<<<grid1, TPB, 0, stream>>>(feat, lengths, ws, S);
        pool_final<<<grid2, TPB, 0, stream>>>(ws, lengths, out);
    } else {
        pool_direct<<<B, TPB, 0, stream>>>(feat, lengths, out, S);
    }
}